// Round 6
// baseline (432.479 us; speedup 1.0000x reference)
//
#include <hip/hip_runtime.h>
#include <math.h>

typedef _Float16 f16x8 __attribute__((ext_vector_type(8)));
typedef float    f32x4 __attribute__((ext_vector_type(4)));
typedef __fp16   fp16x2 __attribute__((ext_vector_type(2)));

#define B_TOT 2048
#define LSEQ  512
#define NS    4            // samples per block; 512 blocks = 2 chains/CU,
                           // each chain = ONE 2-wave block (own barrier)
#define LOG2E 1.44269504088896f
#define LN2   0.69314718055995f

#define MFMA16(A, B, C) __builtin_amdgcn_mfma_f32_16x16x32_f16((A), (B), (C), 0, 0, 0)

__device__ __forceinline__ unsigned int pkrtz(float a, float b) {
    fp16x2 p = __builtin_amdgcn_cvt_pkrtz(a, b);
    return __builtin_bit_cast(unsigned int, p);
}

// 2-wave block. Wave w2 owns features 32*w2..32*w2+31 for ALL 4 gates:
// 8 MFMA tiles t = 2*gt + h' (gate gt, feature half h'), rows
// rho = 64*gt + 32*w2 + 16*h' + (4q + r).  B cols = 4 samples x 4 copies.
// Lane (n,q): ns = n&3, cp = n>>2 -> h' = cp>>1, p' = cp&1; owns the two
// ADJACENT features f,f+1 = 32*w2 + 16*h' + 4*q + 2*p' (+0/1) of sample ns
// -> single packed ds_write_b32 publish.
// h LDS layout: features 8g..8g+7 of sample ns = 4 dwords at 16*g + 4*ns.
// Read banks: 16(q&1)+4ns+d -> 2-way (free, m136). Write: 2 lanes/bank.
__global__ __launch_bounds__(128, 1)
void lstm_v19_kernel(const int* __restrict__ s,
                     const float* __restrict__ W0, const float* __restrict__ b0,
                     const float* __restrict__ Wi, const float* __restrict__ Wh,
                     const float* __restrict__ bh, const float* __restrict__ Wa,
                     const float* __restrict__ ba, const float* __restrict__ Wp,
                     const float* __restrict__ bp, float* __restrict__ out)
{
    const int tid  = threadIdx.x;
    const int w2   = tid >> 6;      // wave 0/1
    const int lane = tid & 63;
    const int n    = lane & 15;
    const int q    = lane >> 4;
    const int ns   = n & 3;
    const int cp   = n >> 2;
    const int hp   = cp >> 1;       // feature half within wave
    const int pp   = cp & 1;        // pair index
    const int b0s  = blockIdx.x * NS;

    __shared__ __align__(16) unsigned int HhD[2][128];  //  1 KB   h exchange
    __shared__ unsigned char  TOKW[LSEQ + 2];           //  0.5 KB
    __shared__ unsigned char  SRAW[NS][LSEQ];           //  2 KB
    __shared__ _Float16 DBUF[LSEQ][NS];                 //  4 KB
    __shared__ float PART[32][NS];                      //  0.5 KB
    __shared__ float PHS[2][NS];

    // ---- stage tokens (coalesced in t) ----
    for (int i = tid; i < NS * LSEQ; i += 128)
        SRAW[i >> 9][i & 511] = (unsigned char)s[(b0s + (i >> 9)) * LSEQ + (i & 511)];
    __syncthreads();
    for (int u = tid; u <= LSEQ; u += 128) {
        unsigned int mask = 0;
        if (u >= 1) {
            #pragma unroll
            for (int m = 0; m < NS; ++m)
                mask |= ((unsigned int)SRAW[m][u - 1]) << m;
        }
        TOKW[u] = (unsigned char)mask;
    }

    // ---- A-frags: scaled Wh^T, 8 tiles ----
    f16x8 awh[8][2];
    #pragma unroll
    for (int t = 0; t < 8; ++t) {
        const int   gt  = t >> 1;
        const float sc  = (gt == 2) ? (2.0f * LOG2E) : (-LOG2E);
        const int   col = 64 * gt + 32 * w2 + 16 * (t & 1) + n;
        #pragma unroll
        for (int c = 0; c < 2; ++c)
            #pragma unroll
            for (int j = 0; j < 8; ++j)
                awh[t][c][j] = (_Float16)(Wh[(32 * c + 8 * q + j) * 256 + col] * sc);
    }

    // ---- d-GEMM A-frag: row 0 = Wa[:,1]-Wa[:,0] ----
    f16x8 awd[2];
    #pragma unroll
    for (int c = 0; c < 2; ++c)
        #pragma unroll
        for (int j = 0; j < 8; ++j) {
            int k = 32 * c + 8 * q + j;
            awd[c][j] = (_Float16)((n == 0) ? (Wa[2 * k + 1] - Wa[2 * k]) : 0.0f);
        }
    const float dba = ba[1] - ba[0];

    // ---- p0/dp (scaled), 8 tiles x 4 rows ----
    f32x4 p0q[8], dpq[8];
    {
        f32x4 A0[8], A1[8];
        #pragma unroll
        for (int t = 0; t < 8; ++t)
            #pragma unroll
            for (int r = 0; r < 4; ++r) {
                float bb = bh[64 * (t >> 1) + 32 * w2 + 16 * (t & 1) + 4 * q + r];
                A0[t][r] = bb; A1[t][r] = bb;
            }
        for (int f = 0; f < 64; ++f) {
            float wb0 = W0[f]      + b0[f];
            float wb1 = W0[64 + f] + b0[f];
            #pragma unroll
            for (int t = 0; t < 8; ++t) {
                const float4 wi4 = *(const float4*)
                    &Wi[f * 256 + 64 * (t >> 1) + 32 * w2 + 16 * (t & 1) + 4 * q];
                #pragma unroll
                for (int r = 0; r < 4; ++r) {
                    float wv = (&wi4.x)[r];
                    A0[t][r] = fmaf(wb0, wv, A0[t][r]);
                    A1[t][r] = fmaf(wb1, wv, A1[t][r]);
                }
            }
        }
        #pragma unroll
        for (int t = 0; t < 8; ++t) {
            const float sc = ((t >> 1) == 2) ? (2.0f * LOG2E) : (-LOG2E);
            #pragma unroll
            for (int r = 0; r < 4; ++r) {
                p0q[t][r] = A0[t][r] * sc;
                dpq[t][r] = (A1[t][r] - A0[t][r]) * sc;
            }
        }
    }

    __syncthreads();   // TOKW ready

    // ---- loop-invariant LDS dword addresses ----
    const int wAddr = 64 * w2 + 32 * hp + 16 * (q >> 1) + 4 * ns + 2 * (q & 1) + pp;
    const int rAddr = 16 * q + 4 * ns;      // bf0; bf1 at +64 dwords

    // ---- state: 2 adjacent-feature cells per lane ----
    float h2[2] = {0.f, 0.f}, c2[2] = {0.f, 0.f};
    f32x4 ci[8];
    #pragma unroll
    for (int t = 0; t < 8; ++t) ci[t] = p0q[t];

    float dpend = 0.0f;
    int   tpend = -1;

    #pragma unroll 2
    for (int v = 0; v <= LSEQ; ++v) {
        const int p = v & 1;
        unsigned int* __restrict__ hb = &HhD[p][0];

        // publish h_{v-1}: one ds_write_b32 (head of serial chain -> first)
        hb[wAddr] = pkrtz(h2[0], h2[1]);
        __syncthreads();

        // flush last rotation's d-result (deadline = post-loop barrier)
        if (tpend >= 0) {
            if (lane < NS) DBUF[tpend][lane] = (_Float16)dpend;
            tpend = -1;
        }

        // B-frags: two ds_read_b128, 2-way banked, 4-lane broadcast
        uint4 r0 = *(const uint4*)&hb[rAddr];
        uint4 r1 = *(const uint4*)&hb[rAddr + 64];
        const f16x8 bf0 = __builtin_bit_cast(f16x8, r0);
        const f16x8 bf1 = __builtin_bit_cast(f16x8, r1);

        const unsigned int tokm_next = (v < LSEQ) ? (unsigned int)TOKW[v + 1] : 0u;

        // gates GEMM: 8 tiles x 2 K-halves
        f32x4 acc[8];
        #pragma unroll
        for (int t = 0; t < 8; ++t) acc[t] = MFMA16(awh[t][0], bf0, ci[t]);
        #pragma unroll
        for (int t = 0; t < 8; ++t) acc[t] = MFMA16(awh[t][1], bf1, acc[t]);

        // rotating wave (every other step): logit-diff for t = v-1
        if (v >= 1 && w2 == (v & 1)) {
            f32x4 da = (f32x4){dba, dba, dba, dba};
            da = MFMA16(awd[0], bf0, da);
            da = MFMA16(awd[1], bf1, da);
            dpend = da[0];
            tpend = v - 1;
        }

        // C-init for next iter (v_pk_fma_f32)
        const float sel = (float)((tokm_next >> ns) & 1u);
        const f32x4 sel4 = {sel, sel, sel, sel};
        #pragma unroll
        for (int t = 0; t < 8; ++t)
            ci[t] = dpq[t] * sel4 + p0q[t];

        // select lane's 2 cells: rows {2p', 2p'+1} of tile 2gt+hp  (6 cnd/gate)
        const bool pb = (pp != 0);
        const bool hbv = (hp != 0);
        float g0[2], g1[2], g2[2], g3[2];
        #pragma unroll
        for (int gt = 0; gt < 4; ++gt) {
            const f32x4 ta = acc[2 * gt];
            const f32x4 tb = acc[2 * gt + 1];
            float z0 = pb ? ta[2] : ta[0];
            float z1 = pb ? ta[3] : ta[1];
            float z2 = pb ? tb[2] : tb[0];
            float z3 = pb ? tb[3] : tb[1];
            float x0 = hbv ? z2 : z0;
            float x1 = hbv ? z3 : z1;
            if (gt == 0) { g0[0] = x0; g0[1] = x1; }
            if (gt == 1) { g1[0] = x0; g1[1] = x1; }
            if (gt == 2) { g2[0] = x0; g2[1] = x1; }
            if (gt == 3) { g3[0] = x0; g3[1] = x1; }
        }

        // activations: 5 exp2 + 2 rcp per cell, 2 cells/lane
        #pragma unroll
        for (int jj = 0; jj < 2; ++jj) {
            float ei = __builtin_amdgcn_exp2f(g0[jj]);                // e^{-i}
            float ef = __builtin_amdgcn_exp2f(g1[jj]);                // e^{-f}
            float eg = __builtin_amdgcn_exp2f(g2[jj]);                // e^{2g}
            float eo = __builtin_amdgcn_exp2f(g3[jj]);                // e^{-o}
            float P  = (1.0f + ei) * (eg + 1.0f);
            float F  = 1.0f + ef;
            float R2 = __builtin_amdgcn_rcpf(P * F);
            float cn = fmaf(c2[jj] * P, R2, (eg - 1.0f) * F * R2);
            c2[jj] = cn;
            float ec = __builtin_amdgcn_exp2f(fminf(cn * (2.0f * LOG2E), 60.f));
            float Ro = __builtin_amdgcn_rcpf((1.0f + eo) * (ec + 1.0f));
            h2[jj] = (ec - 1.0f) * Ro;
        }
    }

    // ---- tail: flush pending d (wave 0, t=511); phase partials from regs ----
    if (tpend >= 0 && lane < NS) DBUF[tpend][lane] = (_Float16)dpend;
    {
        const int f = 32 * w2 + 16 * hp + 4 * q + 2 * pp;
        float ph = fmaf(h2[0], Wp[f], h2[1] * Wp[f + 1]);
        ph += __shfl_xor(ph, 4, 64);     // masks >=4 preserve ns = n&3
        ph += __shfl_xor(ph, 8, 64);
        ph += __shfl_xor(ph, 16, 64);
        ph += __shfl_xor(ph, 32, 64);
        if (lane < NS) PHS[w2][lane] = ph;
    }
    __syncthreads();   // DBUF + PHS visible

    // ---- amp post-pass: 4 samples x 512 t, 16 t/thread ----
    {
        const int nn = tid & 3;
        const int cc = tid >> 2;             // 0..31
        float a = 0.0f;
        #pragma unroll 4
        for (int k = 0; k < 16; ++k) {
            int t = cc * 16 + k;
            float d = (float)DBUF[t][nn];
            float x = SRAW[nn][t] ? -d : d;
            float e = __builtin_amdgcn_exp2f(-fabsf(x) * LOG2E);
            a += fmaxf(x, 0.0f) + __builtin_amdgcn_logf(1.0f + e) * LN2;
        }
        PART[cc][nn] = a;
    }
    __syncthreads();

    if (tid < NS) {
        float ssum = 0.0f;
        #pragma unroll
        for (int c = 0; c < 32; ++c) ssum += PART[c][tid];
        out[b0s + tid] = -0.5f * ssum;                          // planar real
        out[B_TOT + b0s + tid] = PHS[0][tid] + PHS[1][tid] + bp[0];  // imag
    }
}

extern "C" void kernel_launch(void* const* d_in, const int* in_sizes, int n_in,
                              void* d_out, int out_size, void* d_ws, size_t ws_size,
                              hipStream_t stream) {
    const int*   s  = (const int*)  d_in[0];
    const float* W0 = (const float*)d_in[1];
    const float* b0 = (const float*)d_in[2];
    const float* Wi = (const float*)d_in[3];
    const float* Wh = (const float*)d_in[4];
    const float* bh = (const float*)d_in[5];
    const float* Wa = (const float*)d_in[6];
    const float* ba = (const float*)d_in[7];
    const float* Wp = (const float*)d_in[8];
    const float* bp = (const float*)d_in[9];
    float* out = (float*)d_out;

    dim3 grid(B_TOT / NS);   // 512 blocks x 2 waves: 2 chains/CU on disjoint
    dim3 block(128);         // SIMDs, 2-wave barrier, conflict-free h layout
    lstm_v19_kernel<<<grid, block, 0, stream>>>(s, W0, b0, Wi, Wh, bh,
                                                Wa, ba, Wp, bp, out);
}

// Round 7
// 397.072 us; speedup vs baseline: 1.0892x; 1.0892x over previous
//
#include <hip/hip_runtime.h>
#include <math.h>

typedef _Float16 f16x8 __attribute__((ext_vector_type(8)));
typedef float    f32x4 __attribute__((ext_vector_type(4)));
typedef __fp16   fp16x2 __attribute__((ext_vector_type(2)));

#define B_TOT 2048
#define LSEQ  512
#define NSC   4            // samples per chain; 2 chains per block -> 8/block,
                           // 256 blocks, 4 waves, ONE barrier serves both chains
#define LOG2E 1.44269504088896f
#define LN2   0.69314718055995f

#define MFMA16(A, B, C) __builtin_amdgcn_mfma_f32_16x16x32_f16((A), (B), (C), 0, 0, 0)

// Two independent recurrences (A,B) interleaved in ONE instruction stream:
// B's issue fills A's latency (ds_read, MFMA pipe, trans chain) without any
// extra barrier width (v14/v18 lesson) and without v17's register blowup
// (weights shared between chains).
//
// Per chain: 4 samples x 4 col-copies. Wave w owns gate rows 64g+16w..+15.
// Lane(n,q): ns=n&3, cp=n>>2 -> owns 1 cell: feature f=16w+4q+cp, sample ns
// (select acc[g][cp]).
// h LDS layout per chain (128 dwords): feature-chunk c=f>>3 of sample ns at
// dword base 8*ns + 4*(c&1) + 32*((c>>1)&1) + 64*(c>>2)  -> b128 reads hit
// each bank with exactly 2 addresses (free, m136); b16 writes 2 lanes/dword.
__global__ __launch_bounds__(256, 1)
void lstm_v20_kernel(const int* __restrict__ s,
                     const float* __restrict__ W0, const float* __restrict__ b0,
                     const float* __restrict__ Wi, const float* __restrict__ Wh,
                     const float* __restrict__ bh, const float* __restrict__ Wa,
                     const float* __restrict__ ba, const float* __restrict__ Wp,
                     const float* __restrict__ bp, float* __restrict__ out)
{
    const int tid  = threadIdx.x;
    const int w    = tid >> 6;      // wave 0..3: gate-row block 16w (all gates)
    const int lane = tid & 63;
    const int n    = lane & 15;
    const int q    = lane >> 4;
    const int ns   = n & 3;         // sample within chain
    const int cp   = n >> 2;        // copy 0..3 -> acc row r = cp
    const int b0s  = blockIdx.x * 8;

    __shared__ __align__(16) unsigned int HhX[2][2][128];  //  4 KB  h (dbuf x chain)
    __shared__ unsigned char  TOKW[LSEQ + 2];              //  0.5 KB (8-bit masks)
    __shared__ unsigned char  SRAW[8][LSEQ];               //  4 KB
    __shared__ _Float16 DBUF[LSEQ][8];                     //  8 KB
    __shared__ float PART[32][8];                          //  1 KB
    __shared__ float PHS[4][2][NSC];

    // ---- stage tokens (coalesced in t) ----
    for (int i = tid; i < 8 * LSEQ; i += 256)
        SRAW[i >> 9][i & 511] = (unsigned char)s[(b0s + (i >> 9)) * LSEQ + (i & 511)];
    __syncthreads();
    for (int u = tid; u <= LSEQ; u += 256) {
        unsigned int mask = 0;
        if (u >= 1) {
            #pragma unroll
            for (int m = 0; m < 8; ++m)
                mask |= ((unsigned int)SRAW[m][u - 1]) << m;
        }
        TOKW[u] = (unsigned char)mask;
    }

    // ---- A-frags: scaled Wh^T (shared by both chains) ----
    f16x8 awh[4][2];
    #pragma unroll
    for (int g = 0; g < 4; ++g) {
        const float sc  = (g == 2) ? (2.0f * LOG2E) : (-LOG2E);
        const int   col = 64 * g + 16 * w + n;
        #pragma unroll
        for (int c = 0; c < 2; ++c)
            #pragma unroll
            for (int j = 0; j < 8; ++j)
                awh[g][c][j] = (_Float16)(Wh[(32 * c + 8 * q + j) * 256 + col] * sc);
    }

    // ---- d-GEMM A-frag: row 0 = Wa[:,1]-Wa[:,0] (shared) ----
    f16x8 awd[2];
    #pragma unroll
    for (int c = 0; c < 2; ++c)
        #pragma unroll
        for (int j = 0; j < 8; ++j) {
            int k = 32 * c + 8 * q + j;
            awd[c][j] = (_Float16)((n == 0) ? (Wa[2 * k + 1] - Wa[2 * k]) : 0.0f);
        }
    const float dba = ba[1] - ba[0];

    // ---- p0/dp (scaled; shared by both chains) ----
    f32x4 p0q[4], dpq[4];
    {
        float a0[4][4], a1[4][4];
        #pragma unroll
        for (int g = 0; g < 4; ++g)
            #pragma unroll
            for (int r = 0; r < 4; ++r) {
                float bb = bh[64 * g + 16 * w + 4 * q + r];
                a0[g][r] = bb; a1[g][r] = bb;
            }
        for (int f = 0; f < 64; ++f) {
            float wb0 = W0[f]      + b0[f];
            float wb1 = W0[64 + f] + b0[f];
            #pragma unroll
            for (int g = 0; g < 4; ++g) {
                const float4 wi4 = *(const float4*)&Wi[f * 256 + 64 * g + 16 * w + 4 * q];
                #pragma unroll
                for (int r = 0; r < 4; ++r) {
                    float wi = (&wi4.x)[r];
                    a0[g][r] = fmaf(wb0, wi, a0[g][r]);
                    a1[g][r] = fmaf(wb1, wi, a1[g][r]);
                }
            }
        }
        #pragma unroll
        for (int g = 0; g < 4; ++g) {
            const float sc = (g == 2) ? (2.0f * LOG2E) : (-LOG2E);
            #pragma unroll
            for (int r = 0; r < 4; ++r) {
                p0q[g][r] = a0[g][r] * sc;
                dpq[g][r] = (a1[g][r] - a0[g][r]) * sc;
            }
        }
    }

    __syncthreads();   // TOKW ready

    // ---- loop-invariant LDS addresses ----
    // write: lane's cell f = 16w + 4q + cp -> chunk = 2w + ((4q+cp)>>3)
    const int m4    = 4 * q + cp;
    const int bsel  = m4 >> 3;
    const int jj16  = m4 & 7;
    const int chunk = 2 * w + bsel;
    const int baseD = 8 * ns + 4 * (chunk & 1) + 32 * ((chunk >> 1) & 1)
                    + 64 * (chunk >> 2);
    const int wIdx  = 2 * baseD + jj16;                 // b16 slot in chain region
    const int rA    = 8 * ns + 4 * (q & 1) + 32 * (q >> 1);   // bf0; bf1 at +64

    // ---- state: 1 cell per lane per chain ----
    float hA = 0.f, cA = 0.f, hB = 0.f, cB = 0.f;
    f32x4 ciA[4], ciB[4];
    #pragma unroll
    for (int g = 0; g < 4; ++g) { ciA[g] = p0q[g]; ciB[g] = p0q[g]; }

    float dpA = 0.f, dpB = 0.f;
    int   tpA = -1,  tpB = -1;

    #pragma unroll 4
    for (int v = 0; v <= LSEQ; ++v) {
        const int p = v & 1;
        _Float16* __restrict__ h16A = (_Float16*)&HhX[p][0][0];
        _Float16* __restrict__ h16B = (_Float16*)&HhX[p][1][0];

        // publish h_{v-1} for both chains (head of serial chain -> first)
        h16A[wIdx] = (_Float16)hA;
        h16B[wIdx] = (_Float16)hB;
        __syncthreads();

        // B-frags first (critical path); latencies of A and B overlap
        const uint4 ra0 = *(const uint4*)&HhX[p][0][rA];
        const uint4 ra1 = *(const uint4*)&HhX[p][0][rA + 64];
        const uint4 rb0 = *(const uint4*)&HhX[p][1][rA];
        const uint4 rb1 = *(const uint4*)&HhX[p][1][rA + 64];
        const f16x8 bfA0 = __builtin_bit_cast(f16x8, ra0);
        const f16x8 bfA1 = __builtin_bit_cast(f16x8, ra1);
        const f16x8 bfB0 = __builtin_bit_cast(f16x8, rb0);
        const f16x8 bfB1 = __builtin_bit_cast(f16x8, rb1);

        // flush deferred d-results AFTER the reads (DS is in-order per wave)
        if (tpA >= 0) { if (lane < NSC) DBUF[tpA][lane] = (_Float16)dpA; tpA = -1; }
        if (tpB >= 0) { if (lane < NSC) DBUF[tpB][4 + lane] = (_Float16)dpB; tpB = -1; }

        const unsigned int tok = (v < LSEQ) ? (unsigned int)TOKW[v + 1] : 0u;

        // gates GEMM, A/B interleaved (B fills A's MFMA latency)
        f32x4 aA0 = ciA[0], aA1 = ciA[1], aA2 = ciA[2], aA3 = ciA[3];
        f32x4 aB0 = ciB[0], aB1 = ciB[1], aB2 = ciB[2], aB3 = ciB[3];
        aA0 = MFMA16(awh[0][0], bfA0, aA0);  aB0 = MFMA16(awh[0][0], bfB0, aB0);
        aA1 = MFMA16(awh[1][0], bfA0, aA1);  aB1 = MFMA16(awh[1][0], bfB0, aB1);
        aA2 = MFMA16(awh[2][0], bfA0, aA2);  aB2 = MFMA16(awh[2][0], bfB0, aB2);
        aA3 = MFMA16(awh[3][0], bfA0, aA3);  aB3 = MFMA16(awh[3][0], bfB0, aB3);
        aA0 = MFMA16(awh[0][1], bfA1, aA0);  aB0 = MFMA16(awh[0][1], bfB1, aB0);
        aA1 = MFMA16(awh[1][1], bfA1, aA1);  aB1 = MFMA16(awh[1][1], bfB1, aB1);
        aA2 = MFMA16(awh[2][1], bfA1, aA2);  aB2 = MFMA16(awh[2][1], bfB1, aB2);
        aA3 = MFMA16(awh[3][1], bfA1, aA3);  aB3 = MFMA16(awh[3][1], bfB1, aB3);

        // rotating d-GEMMs (staggered: wave v&3 does A, wave (v+2)&3 does B)
        if (v >= 1 && w == (v & 3)) {
            f32x4 da = (f32x4){dba, dba, dba, dba};
            da = MFMA16(awd[0], bfA0, da);
            da = MFMA16(awd[1], bfA1, da);
            dpA = da[0];
            tpA = v - 1;
        }
        if (v >= 1 && w == ((v + 2) & 3)) {
            f32x4 db = (f32x4){dba, dba, dba, dba};
            db = MFMA16(awd[0], bfB0, db);
            db = MFMA16(awd[1], bfB1, db);
            dpB = db[0];
            tpB = v - 1;
        }

        // C-init for next iter (token-dependent per chain)
        const float sA = (float)((tok >> ns) & 1u);
        const float sB = (float)((tok >> (4 + ns)) & 1u);
        const f32x4 sA4 = {sA, sA, sA, sA};
        const f32x4 sB4 = {sB, sB, sB, sB};
        #pragma unroll
        for (int g = 0; g < 4; ++g) {
            ciA[g] = dpq[g] * sA4 + p0q[g];
            ciB[g] = dpq[g] * sB4 + p0q[g];
        }

        // select lane's cell (row r = cp) and run activation, both chains
        const bool s1 = (cp & 1) != 0;
        const bool s2 = (cp & 2) != 0;
        #pragma unroll
        for (int cc = 0; cc < 2; ++cc) {
            const f32x4 x0 = cc ? aB0 : aA0;
            const f32x4 x1 = cc ? aB1 : aA1;
            const f32x4 x2 = cc ? aB2 : aA2;
            const f32x4 x3 = cc ? aB3 : aA3;
            float gi = s2 ? (s1 ? x0[3] : x0[2]) : (s1 ? x0[1] : x0[0]);
            float gf = s2 ? (s1 ? x1[3] : x1[2]) : (s1 ? x1[1] : x1[0]);
            float gg = s2 ? (s1 ? x2[3] : x2[2]) : (s1 ? x2[1] : x2[0]);
            float go = s2 ? (s1 ? x3[3] : x3[2]) : (s1 ? x3[1] : x3[0]);
            float ei = __builtin_amdgcn_exp2f(gi);                // e^{-i}
            float ef = __builtin_amdgcn_exp2f(gf);                // e^{-f}
            float eg = __builtin_amdgcn_exp2f(gg);                // e^{2g}
            float eo = __builtin_amdgcn_exp2f(go);                // e^{-o}
            float P  = (1.0f + ei) * (eg + 1.0f);
            float F  = 1.0f + ef;
            float R2 = __builtin_amdgcn_rcpf(P * F);
            float cold = cc ? cB : cA;
            float cn = fmaf(cold * P, R2, (eg - 1.0f) * F * R2);
            float ec = __builtin_amdgcn_exp2f(fminf(cn * (2.0f * LOG2E), 60.f));
            float Ro = __builtin_amdgcn_rcpf((1.0f + eo) * (ec + 1.0f));
            float hn = (ec - 1.0f) * Ro;
            if (cc) { cB = cn; hB = hn; } else { cA = cn; hA = hn; }
        }
    }

    // ---- tail: flush pending d (wave0: A t=511; wave2: B t=511) ----
    if (tpA >= 0 && lane < NSC) DBUF[tpA][lane] = (_Float16)dpA;
    if (tpB >= 0 && lane < NSC) DBUF[tpB][4 + lane] = (_Float16)dpB;

    // phase partials from registers (1 feature/lane/chain)
    {
        const int f = 16 * w + 4 * q + cp;
        float phA = hA * Wp[f];
        float phB = hB * Wp[f];
        phA += __shfl_xor(phA, 4, 64);  phB += __shfl_xor(phB, 4, 64);
        phA += __shfl_xor(phA, 8, 64);  phB += __shfl_xor(phB, 8, 64);
        phA += __shfl_xor(phA, 16, 64); phB += __shfl_xor(phB, 16, 64);
        phA += __shfl_xor(phA, 32, 64); phB += __shfl_xor(phB, 32, 64);
        if (lane < NSC) { PHS[w][0][lane] = phA; PHS[w][1][lane] = phB; }
    }
    __syncthreads();   // DBUF + PHS visible

    // ---- amp post-pass: 8 samples x 512 t, 16 t/thread ----
    {
        const int nn = tid & 7;
        const int cc = tid >> 3;             // 0..31
        float a = 0.0f;
        #pragma unroll 4
        for (int k = 0; k < 16; ++k) {
            int t = cc * 16 + k;
            float d = (float)DBUF[t][nn];
            float x = SRAW[nn][t] ? -d : d;
            float e = __builtin_amdgcn_exp2f(-fabsf(x) * LOG2E);
            a += fmaxf(x, 0.0f) + __builtin_amdgcn_logf(1.0f + e) * LN2;
        }
        PART[cc][nn] = a;
    }
    __syncthreads();

    if (tid < 8) {
        float ssum = 0.0f;
        #pragma unroll
        for (int c = 0; c < 32; ++c) ssum += PART[c][tid];
        out[b0s + tid] = -0.5f * ssum;                       // planar real
        float ph = PHS[0][tid >> 2][tid & 3] + PHS[1][tid >> 2][tid & 3]
                 + PHS[2][tid >> 2][tid & 3] + PHS[3][tid >> 2][tid & 3];
        out[B_TOT + b0s + tid] = ph + bp[0];                 // planar imag
    }
}

extern "C" void kernel_launch(void* const* d_in, const int* in_sizes, int n_in,
                              void* d_out, int out_size, void* d_ws, size_t ws_size,
                              hipStream_t stream) {
    const int*   s  = (const int*)  d_in[0];
    const float* W0 = (const float*)d_in[1];
    const float* b0 = (const float*)d_in[2];
    const float* Wi = (const float*)d_in[3];
    const float* Wh = (const float*)d_in[4];
    const float* bh = (const float*)d_in[5];
    const float* Wa = (const float*)d_in[6];
    const float* ba = (const float*)d_in[7];
    const float* Wp = (const float*)d_in[8];
    const float* bp = (const float*)d_in[9];
    float* out = (float*)d_out;

    dim3 grid(B_TOT / 8);    // 256 WGs x 4 waves; 2 in-wave chains share one
    dim3 block(256);         // barrier -> barrier+latency residue amortized 2x
    lstm_v20_kernel<<<grid, block, 0, stream>>>(s, W0, b0, Wi, Wh, bh,
                                                Wa, ba, Wp, bp, out);
}